// Round 1
// 197.668 us; speedup vs baseline: 1.0355x; 1.0355x over previous
//
#include <hip/hip_runtime.h>
#include <stdint.h>

typedef __attribute__((ext_vector_type(4))) float floatx4;
typedef __attribute__((ext_vector_type(8))) __bf16 bf16x8;

#define K_DIM 2048
#define NH 96
#define M_ROWS 16384
#define BK 32
#define KSLICE (K_DIM / 4)            // 512 per wave (4 waves cover full K)
#define STEPS (KSLICE / BK)           // 16
#define NSLAB (K_DIM / BK)            // 64
#define WSLAB 6144                    // 6 frags * 1 KB, tight (no pad needed now)
#define WPACK_BYTES (NSLAB * WSLAB)   // 393216
#define RS 100                        // padded row stride (floats) for epilogue reduce

// async global->LDS, 16B/lane; LDS dest = wave-uniform base (+ lane*16 implicit)
#define GLD16(gp, lp) __builtin_amdgcn_global_load_lds( \
    (const __attribute__((address_space(1))) uint32_t*)(gp), \
    (__attribute__((address_space(3))) uint32_t*)(lp), 16, 0, 0)

// s_waitcnt imm: vmcnt[3:0]|[15:14], expcnt[6:4], lgkmcnt[11:8].
// Wait until <= n vm-ops outstanding AND lgkmcnt==0. Memory clobbers pin the
// ds_read/GLD16 ordering around the wait (same-wave consumption, no barrier).
#define WAIT_VM_LGKM0(n) do { asm volatile("" ::: "memory"); \
    __builtin_amdgcn_s_waitcnt((0 << 8) | (7 << 4) | (n)); \
    asm volatile("" ::: "memory"); } while (0)
// lgkmcnt(0) only; vmcnt unconstrained (63). Guards LDS WAR before re-staging.
#define WAIT_LGKM0() do { asm volatile("" ::: "memory"); \
    __builtin_amdgcn_s_waitcnt((3u << 14) | (0 << 8) | (7 << 4) | 15); \
    asm volatile("" ::: "memory"); } while (0)

// --- Kernel 1: pack W into bf16 B-frags, BK=32 slabs, tight 6 KB slab stride.
// Frag (s,t), lane l, elem j = W[t*16+(l&15)][s*32+(l>>4)*8+j]   (layout verified)
__global__ __launch_bounds__(256) void wpack_kernel(const float* __restrict__ W,
                                                    uint8_t* __restrict__ WbF) {
    int u = blockIdx.x * 256 + threadIdx.x;   // 0..24575 = 64 slabs * 6 frags * 64 lanes
    int l  = u & 63;
    int fr = u >> 6;
    int t  = fr % 6;
    int s  = fr / 6;
    int head = t * 16 + (l & 15);
    int k    = s * 32 + (l >> 4) * 8;
    const float* wp = W + (size_t)head * K_DIM + k;
    float4 v0 = *(const float4*)wp;
    float4 v1 = *(const float4*)(wp + 4);
    bf16x8 o;
    o[0] = (__bf16)v0.x; o[1] = (__bf16)v0.y; o[2] = (__bf16)v0.z; o[3] = (__bf16)v0.w;
    o[4] = (__bf16)v1.x; o[5] = (__bf16)v1.y; o[6] = (__bf16)v1.z; o[7] = (__bf16)v1.w;
    *(bf16x8*)(WbF + (size_t)s * WSLAB + t * 1024 + l * 16) = o;
}

// --- Kernel 2: fused GEMM, intra-block K-split, barrier-free K-loop.
// Block: 32 output rows x 96 heads. Wave w owns K range [w*512, w*512+512).
// Each wave stages & reads ONLY its own LDS regions -> no s_barrier in the loop.
// Double-buffered: per wave per buffer 4 KB x + 6 KB W; block LDS = 80 KB -> 2 blk/CU.
// Epilogue: 4-wave accumulator reduce in LDS + bias, direct coalesced out write.
__global__ __launch_bounds__(256, 2) void mh_gemm_kernel(const float* __restrict__ x,
                                                         const uint8_t* __restrict__ WbF,
                                                         const float* __restrict__ bias,
                                                         float* __restrict__ out) {
    __shared__ __align__(16) uint8_t smem[2][4][10240];  // [buf][wave][4KB x | 6KB W]

    const int tid  = threadIdx.x;
    const int w    = tid >> 6;
    const int lane = tid & 63;
    const int n15  = lane & 15;
    const int quad = lane >> 4;
    const int m0   = (int)blockIdx.x * 32;

    // x staging: lane -> (row = lane>>3, chunk = lane&7); global chunk = (lane&7)^(row&7)
    // so LDS slot c of row r holds global chunk c^(r&7). Coalesced 128B/row.
    const float* xg0 = x + (size_t)(m0 + (lane >> 3)) * K_DIM
                         + (size_t)w * KSLICE
                         + (((lane & 7) ^ ((lane >> 3) & 7)) << 2);
    // wave w's W slabs: slab index w*16 + s
    const uint8_t* wg0 = WbF + (size_t)(w * STEPS) * WSLAB + lane * 16;

    auto stage = [&](int s, int bsel) {
        uint8_t* xb = &smem[bsel][w][0];
        const float* xg = xg0 + s * BK;
        GLD16(xg,              xb + 0 * 1024);
        GLD16(xg +  8 * K_DIM, xb + 1 * 1024);
        GLD16(xg + 16 * K_DIM, xb + 2 * 1024);
        GLD16(xg + 24 * K_DIM, xb + 3 * 1024);
        const uint8_t* wg = wg0 + (size_t)s * WSLAB;
        uint8_t* wb = xb + 4096;
#pragma unroll
        for (int t = 0; t < 6; ++t)
            GLD16(wg + t * 1024, wb + t * 1024);
    };

    floatx4 acc[2][6] = {};

    auto compute = [&](int bsel) {
        const float* xsw = (const float*)&smem[bsel][w][0];
        bf16x8 af[2];
#pragma unroll
        for (int h = 0; h < 2; ++h) {
            const int R = h * 16 + n15;
            const float* rowp = xsw + R * 32;
            const int sw = n15 & 7;
            float4 lo = *(const float4*)(rowp + (((quad * 2    ) ^ sw) << 2));
            float4 hi = *(const float4*)(rowp + (((quad * 2 + 1) ^ sw) << 2));
            bf16x8 a;
            a[0] = (__bf16)lo.x; a[1] = (__bf16)lo.y;
            a[2] = (__bf16)lo.z; a[3] = (__bf16)lo.w;
            a[4] = (__bf16)hi.x; a[5] = (__bf16)hi.y;
            a[6] = (__bf16)hi.z; a[7] = (__bf16)hi.w;
            af[h] = a;
        }
        const uint8_t* wsb = &smem[bsel][w][4096];
#pragma unroll
        for (int t = 0; t < 6; ++t) {
            uint4 bw = *(const uint4*)(wsb + t * 1024 + lane * 16);
            bf16x8 bb = __builtin_bit_cast(bf16x8, bw);
            acc[0][t] = __builtin_amdgcn_mfma_f32_16x16x32_bf16(af[0], bb, acc[0][t], 0, 0, 0);
            acc[1][t] = __builtin_amdgcn_mfma_f32_16x16x32_bf16(af[1], bb, acc[1][t], 0, 0, 0);
        }
    };

    stage(0, 0);      // 10 loads
    stage(1, 1);      // 10 loads -> 20 outstanding
    for (int s = 0; s < STEPS; ++s) {
        // steady state: slab s+1's 10 loads stay in flight; slab s forced complete.
        if (s < STEPS - 1) WAIT_VM_LGKM0(10);
        else               WAIT_VM_LGKM0(0);
        compute(s & 1);
        if (s + 2 < STEPS) {
            WAIT_LGKM0();          // all ds_reads of buf (s&1) drained before overwrite
            stage(s + 2, s & 1);
        }
    }

    // --- epilogue: cross-wave K reduction in LDS, + bias, direct out write ---
    __syncthreads();               // staging fully consumed; safe to repurpose LDS
    float* red = (float*)&smem[0][0][0];   // 4 waves * 32 rows * RS floats = 51200 B
    {
        float* rw = red + w * (32 * RS);
#pragma unroll
        for (int h = 0; h < 2; ++h)
#pragma unroll
            for (int t = 0; t < 6; ++t)
#pragma unroll
                for (int r = 0; r < 4; ++r)
                    // C/D: col=n15, row=quad*4+r [m89-verified]
                    rw[(h * 16 + quad * 4 + r) * RS + t * 16 + n15] = acc[h][t][r];
    }
    __syncthreads();
#pragma unroll
    for (int k = 0; k < 3; ++k) {
        int e4   = k * 256 + tid;          // 768 float4 outputs (32*96/4)
        int e    = e4 * 4;
        int row  = e / NH;
        int head = e % NH;                 // multiple of 4
        const float* r0 = red + row * RS + head;
        float4 s0 = *(const float4*)(r0);
        float4 s1 = *(const float4*)(r0 + 1 * 32 * RS);
        float4 s2 = *(const float4*)(r0 + 2 * 32 * RS);
        float4 s3 = *(const float4*)(r0 + 3 * 32 * RS);
        float4 bv = *(const float4*)(bias + head);
        float4 o;
        o.x = s0.x + s1.x + s2.x + s3.x + bv.x;
        o.y = s0.y + s1.y + s2.y + s3.y + bv.y;
        o.z = s0.z + s1.z + s2.z + s3.z + bv.z;
        o.w = s0.w + s1.w + s2.w + s3.w + bv.w;
        *(float4*)(out + (size_t)(m0 + row) * NH + head) = o;
    }
}

extern "C" void kernel_launch(void* const* d_in, const int* in_sizes, int n_in,
                              void* d_out, int out_size, void* d_ws, size_t ws_size,
                              hipStream_t stream) {
    const float* x = (const float*)d_in[0];
    const float* W = (const float*)d_in[1];
    const float* b = (const float*)d_in[2];
    float* out = (float*)d_out;

    uint8_t* WbF = (uint8_t*)d_ws;   // 384 KB (only workspace use now)

    wpack_kernel<<<96, 256, 0, stream>>>(W, WbF);
    mh_gemm_kernel<<<M_ROWS / 32, 256, 0, stream>>>(x, WbF, b, out);
}